// Round 1
// baseline (7198.234 us; speedup 1.0000x reference)
//
#include <hip/hip_runtime.h>
#include <hip/hip_bf16.h>

#define N_NODES 100000
#define N_EDGES 1600000
#define F_IN 128
#define F_HID 256
#define F_OUT 128

// ---------------- degree ----------------
__global__ __launch_bounds__(256) void deg_kernel(const int* __restrict__ dst,
                                                  float* __restrict__ deg, int n) {
    int i = blockIdx.x * 256 + threadIdx.x;
    if (i < n) atomicAdd(&deg[dst[i]], 1.0f);
}

__global__ __launch_bounds__(256) void invdeg_kernel(const float* __restrict__ deg,
                                                     float* __restrict__ inv, int n) {
    int i = blockIdx.x * 256 + threadIdx.x;
    if (i < n) inv[i] = 1.0f / fmaxf(deg[i], 1.0f);
}

// ---------------- scatter-add aggregation ----------------
// one wave (64 lanes) per edge; each lane owns F/64 consecutive floats
template <int F>
__global__ __launch_bounds__(256) void scatter_add_kernel(const float* __restrict__ H,
                                                          const int* __restrict__ src,
                                                          const int* __restrict__ dst,
                                                          float* __restrict__ out,
                                                          int nEdges) {
    int lane = threadIdx.x & 63;
    int wid = blockIdx.x * 4 + (threadIdx.x >> 6);
    if (wid >= nEdges) return;
    int s = src[wid];
    int d = dst[wid];
    constexpr int C = F / 64;  // 2 or 4
    const float* hp = H + (size_t)s * F + lane * C;
    float* op = out + (size_t)d * F + lane * C;
    if constexpr (C == 2) {
        float2 v = *(const float2*)hp;
        atomicAdd(op + 0, v.x);
        atomicAdd(op + 1, v.y);
    } else {
        float4 v = *(const float4*)hp;
        atomicAdd(op + 0, v.x);
        atomicAdd(op + 1, v.y);
        atomicAdd(op + 2, v.z);
        atomicAdd(op + 3, v.w);
    }
}

// ---------------- fused concat-K GEMM ----------------
// C[M,N] = [A1 | A2*invdeg] @ [W1 ; W2] + bias, optional sigmoid.
// BM=64, BN=64, BK=32, 256 threads, 4x4 acc per thread.
#define BM 64
#define BN 64
#define BK 32

__global__ __launch_bounds__(256) void gemm_cat_kernel(
    const float* __restrict__ A1, int lda1,
    const float* __restrict__ A2, int lda2,
    const float* __restrict__ invdeg,
    const float* __restrict__ W1,  // (Kx, N)
    const float* __restrict__ W2,  // (Ktot-Kx, N)
    const float* __restrict__ bias,
    float* __restrict__ C,
    int M, int N, int Kx, int Ktot, int applySigmoid) {
    __shared__ float As[BK][BM + 4];  // +4 pad: keeps float4 alignment (68*4=272B) & spreads banks
    __shared__ float Bs[BK][BN];

    int tid = threadIdx.x;
    int bm = blockIdx.x * BM;
    int bn = blockIdx.y * BN;

    int tx = tid & 15;   // col group (4 cols each)
    int ty = tid >> 4;   // row group (4 rows each)

    float acc[4][4] = {{0.f}};

    for (int k0 = 0; k0 < Ktot; k0 += BK) {
        bool isA2 = (k0 >= Kx);
        // ---- A tile: 64 rows x 32 k (2048 elems = 2 float4/thread) ----
#pragma unroll
        for (int t = 0; t < 2; ++t) {
            int idx = tid + t * 256;       // 0..511
            int m = idx >> 3;              // 0..63
            int k4 = (idx & 7) * 4;        // 0,4,..,28
            int row = bm + m;
            float4 v = make_float4(0.f, 0.f, 0.f, 0.f);
            if (row < M) {
                if (!isA2) {
                    v = *(const float4*)(A1 + (size_t)row * lda1 + (k0 + k4));
                } else {
                    v = *(const float4*)(A2 + (size_t)row * lda2 + (k0 - Kx + k4));
                    float s = invdeg[row];
                    v.x *= s; v.y *= s; v.z *= s; v.w *= s;
                }
            }
            As[k4 + 0][m] = v.x;
            As[k4 + 1][m] = v.y;
            As[k4 + 2][m] = v.z;
            As[k4 + 3][m] = v.w;
        }
        // ---- B tile: 32 k x 64 n (2048 elems = 2 float4/thread) ----
#pragma unroll
        for (int t = 0; t < 2; ++t) {
            int idx = tid + t * 256;
            int k = idx >> 4;              // 0..31
            int n4 = (idx & 15) * 4;       // 0..60
            int kk = k0 + k;
            const float* Wp = (kk < Kx) ? (W1 + (size_t)kk * N)
                                        : (W2 + (size_t)(kk - Kx) * N);
            *(float4*)&Bs[k][n4] = *(const float4*)(Wp + bn + n4);
        }
        __syncthreads();
#pragma unroll
        for (int k = 0; k < BK; ++k) {
            float4 av = *(const float4*)&As[k][ty * 4];
            float4 bv = *(const float4*)&Bs[k][tx * 4];
            float a[4] = {av.x, av.y, av.z, av.w};
            float b[4] = {bv.x, bv.y, bv.z, bv.w};
#pragma unroll
            for (int i = 0; i < 4; ++i)
#pragma unroll
                for (int j = 0; j < 4; ++j) acc[i][j] += a[i] * b[j];
        }
        __syncthreads();
    }

    // ---- epilogue ----
#pragma unroll
    for (int i = 0; i < 4; ++i) {
        int row = bm + ty * 4 + i;
        if (row >= M) continue;
#pragma unroll
        for (int j = 0; j < 4; ++j) {
            int col = bn + tx * 4 + j;
            float v = acc[i][j] + bias[col];
            if (applySigmoid) v = 1.0f / (1.0f + expf(-v));
            C[(size_t)row * N + col] = v;
        }
    }
}

extern "C" void kernel_launch(void* const* d_in, const int* in_sizes, int n_in,
                              void* d_out, int out_size, void* d_ws, size_t ws_size,
                              hipStream_t stream) {
    const float* x       = (const float*)d_in[0];
    const int*   src     = (const int*)d_in[1];
    const int*   dst     = (const int*)d_in[2];
    const float* W_self1 = (const float*)d_in[3];
    const float* W_neigh1= (const float*)d_in[4];
    const float* b1      = (const float*)d_in[5];
    const float* W_self2 = (const float*)d_in[6];
    const float* W_neigh2= (const float*)d_in[7];
    const float* b2      = (const float*)d_in[8];
    float* out = (float*)d_out;

    // workspace layout (floats)
    float* ws   = (float*)d_ws;
    float* deg    = ws;                        // 100000
    float* invdeg = ws + N_NODES;              // 100000
    float* buf    = ws + 2 * N_NODES;          // 100000*256 (used as 128-wide in layer 1)
    float* h      = buf + (size_t)N_NODES * F_HID;  // 100000*256

    // ---- zero deg + neigh buffer (layer 1 needs first 128 cols) ----
    hipMemsetAsync(deg, 0, (size_t)N_NODES * sizeof(float), stream);
    hipMemsetAsync(buf, 0, (size_t)N_NODES * F_IN * sizeof(float), stream);

    // ---- degree ----
    deg_kernel<<<(N_EDGES + 255) / 256, 256, 0, stream>>>(dst, deg, N_EDGES);
    invdeg_kernel<<<(N_NODES + 255) / 256, 256, 0, stream>>>(deg, invdeg, N_NODES);

    // ---- layer 1 aggregation: buf = segment_sum(x[src], dst) ----
    scatter_add_kernel<F_IN><<<(N_EDGES + 3) / 4, 256, 0, stream>>>(x, src, dst, buf, N_EDGES);

    // ---- layer 1 GEMM: h = sigmoid([x | buf*invdeg] @ [Ws1;Wn1] + b1) ----
    {
        dim3 grid((N_NODES + BM - 1) / BM, F_HID / BN);
        gemm_cat_kernel<<<grid, 256, 0, stream>>>(
            x, F_IN, buf, F_IN, invdeg, W_self1, W_neigh1, b1, h,
            N_NODES, F_HID, F_IN, F_IN + F_IN, 1);
    }

    // ---- zero neigh buffer for layer 2 (256 wide) ----
    hipMemsetAsync(buf, 0, (size_t)N_NODES * F_HID * sizeof(float), stream);

    // ---- layer 2 aggregation: buf = segment_sum(h[src], dst) ----
    scatter_add_kernel<F_HID><<<(N_EDGES + 3) / 4, 256, 0, stream>>>(h, src, dst, buf, N_EDGES);

    // ---- layer 2 GEMM: out = [h | buf*invdeg] @ [Ws2;Wn2] + b2 ----
    {
        dim3 grid((N_NODES + BM - 1) / BM, F_OUT / BN);
        gemm_cat_kernel<<<grid, 256, 0, stream>>>(
            h, F_HID, buf, F_HID, invdeg, W_self2, W_neigh2, b2, out,
            N_NODES, F_OUT, F_HID, F_HID + F_HID, 0);
    }
}

// Round 2
// 933.438 us; speedup vs baseline: 7.7115x; 7.7115x over previous
//
#include <hip/hip_runtime.h>
#include <hip/hip_bf16.h>

#define N_NODES 100000
#define N_EDGES 1600000
#define F_IN 128
#define F_HID 256
#define F_OUT 128

// ---------------- CSR build ----------------
__global__ __launch_bounds__(256) void deg_count_kernel(const int* __restrict__ dst,
                                                        int* __restrict__ cnt, int n) {
    int i = blockIdx.x * 256 + threadIdx.x;
    if (i < n) atomicAdd(&cnt[dst[i]], 1);
}

__global__ __launch_bounds__(256) void invdeg_kernel(const int* __restrict__ cnt,
                                                     float* __restrict__ inv, int n) {
    int i = blockIdx.x * 256 + threadIdx.x;
    if (i < n) inv[i] = 1.0f / fmaxf((float)cnt[i], 1.0f);
}

// hierarchical exclusive scan over n=100000 ints
__global__ __launch_bounds__(1024) void scan1_kernel(const int* __restrict__ cnt,
                                                     int* __restrict__ rowptr,
                                                     int* __restrict__ blockSums, int n) {
    __shared__ int tmp[1024];
    int tid = threadIdx.x;
    int i = blockIdx.x * 1024 + tid;
    int v = (i < n) ? cnt[i] : 0;
    tmp[tid] = v;
    __syncthreads();
#pragma unroll
    for (int off = 1; off < 1024; off <<= 1) {
        int t = (tid >= off) ? tmp[tid - off] : 0;
        __syncthreads();
        tmp[tid] += t;
        __syncthreads();
    }
    if (i < n) rowptr[i] = tmp[tid] - v;  // exclusive
    if (tid == 1023) blockSums[blockIdx.x] = tmp[1023];
}

__global__ __launch_bounds__(128) void scan2_kernel(int* __restrict__ blockSums, int nb) {
    __shared__ int tmp[128];
    int tid = threadIdx.x;
    int v = (tid < nb) ? blockSums[tid] : 0;
    tmp[tid] = v;
    __syncthreads();
#pragma unroll
    for (int off = 1; off < 128; off <<= 1) {
        int t = (tid >= off) ? tmp[tid - off] : 0;
        __syncthreads();
        tmp[tid] += t;
        __syncthreads();
    }
    if (tid < nb) blockSums[tid] = tmp[tid] - v;  // exclusive block offsets
}

__global__ __launch_bounds__(1024) void scan3_kernel(int* __restrict__ rowptr,
                                                     int* __restrict__ cursor,
                                                     const int* __restrict__ blockSums, int n) {
    int i = blockIdx.x * 1024 + threadIdx.x;
    if (i < n) {
        int v = rowptr[i] + blockSums[blockIdx.x];
        rowptr[i] = v;
        cursor[i] = v;
    }
    if (i == 0) rowptr[n] = N_EDGES;
}

__global__ __launch_bounds__(256) void fill_csr_kernel(const int* __restrict__ src,
                                                       const int* __restrict__ dst,
                                                       int* __restrict__ cursor,
                                                       int* __restrict__ csr_src, int n) {
    int i = blockIdx.x * 256 + threadIdx.x;
    if (i < n) {
        int p = atomicAdd(&cursor[dst[i]], 1);
        csr_src[p] = src[i];
    }
}

// ---------------- gather aggregation (one wave per node) ----------------
template <int F>
__global__ __launch_bounds__(256) void gather_kernel(const float* __restrict__ H,
                                                     const int* __restrict__ rowptr,
                                                     const int* __restrict__ csr_src,
                                                     float* __restrict__ out, int nNodes) {
    int lane = threadIdx.x & 63;
    int node = blockIdx.x * 4 + (threadIdx.x >> 6);
    if (node >= nNodes) return;
    int start = rowptr[node], end = rowptr[node + 1];
    constexpr int C = F / 64;  // 2 for F=128
    float acc[C] = {};
    for (int e = start; e < end; ++e) {
        int s = csr_src[e];
        const float* hp = H + (size_t)s * F + lane * C;
        if constexpr (C == 2) {
            float2 v = *(const float2*)hp;
            acc[0] += v.x; acc[1] += v.y;
        } else {
            float4 v = *(const float4*)hp;
            acc[0] += v.x; acc[1] += v.y; acc[2] += v.z; acc[3] += v.w;
        }
    }
    float* op = out + (size_t)node * F + lane * C;
    if constexpr (C == 2) {
        *(float2*)op = make_float2(acc[0], acc[1]);
    } else {
        *(float4*)op = make_float4(acc[0], acc[1], acc[2], acc[3]);
    }
}

// ---------------- fused GEMM ----------------
// C[M,N] = [A1 | A2*invdeg] @ [W1 ; W2] + bias + addend*invdeg, optional sigmoid.
// A2, bias, addend may be null.
#define BM 64
#define BN 64
#define BK 32

__global__ __launch_bounds__(256) void gemm_cat_kernel(
    const float* __restrict__ A1, int lda1,
    const float* __restrict__ A2, int lda2,
    const float* __restrict__ invdeg,
    const float* __restrict__ W1,  // (Kx, N)
    const float* __restrict__ W2,  // (Ktot-Kx, N)
    const float* __restrict__ bias,
    const float* __restrict__ addend,  // (M, N) scaled by invdeg[row]
    float* __restrict__ C,
    int M, int N, int Kx, int Ktot, int applySigmoid) {
    __shared__ float As[BK][BM + 4];
    __shared__ float Bs[BK][BN];

    int tid = threadIdx.x;
    int bm = blockIdx.x * BM;
    int bn = blockIdx.y * BN;

    int tx = tid & 15;
    int ty = tid >> 4;

    float acc[4][4] = {{0.f}};

    for (int k0 = 0; k0 < Ktot; k0 += BK) {
        bool isA2 = (k0 >= Kx);
#pragma unroll
        for (int t = 0; t < 2; ++t) {
            int idx = tid + t * 256;
            int m = idx >> 3;
            int k4 = (idx & 7) * 4;
            int row = bm + m;
            float4 v = make_float4(0.f, 0.f, 0.f, 0.f);
            if (row < M) {
                if (!isA2) {
                    v = *(const float4*)(A1 + (size_t)row * lda1 + (k0 + k4));
                } else {
                    v = *(const float4*)(A2 + (size_t)row * lda2 + (k0 - Kx + k4));
                    float s = invdeg[row];
                    v.x *= s; v.y *= s; v.z *= s; v.w *= s;
                }
            }
            As[k4 + 0][m] = v.x;
            As[k4 + 1][m] = v.y;
            As[k4 + 2][m] = v.z;
            As[k4 + 3][m] = v.w;
        }
#pragma unroll
        for (int t = 0; t < 2; ++t) {
            int idx = tid + t * 256;
            int k = idx >> 4;
            int n4 = (idx & 15) * 4;
            int kk = k0 + k;
            const float* Wp = (kk < Kx) ? (W1 + (size_t)kk * N)
                                        : (W2 + (size_t)(kk - Kx) * N);
            *(float4*)&Bs[k][n4] = *(const float4*)(Wp + bn + n4);
        }
        __syncthreads();
#pragma unroll
        for (int k = 0; k < BK; ++k) {
            float4 av = *(const float4*)&As[k][ty * 4];
            float4 bv = *(const float4*)&Bs[k][tx * 4];
            float a[4] = {av.x, av.y, av.z, av.w};
            float b[4] = {bv.x, bv.y, bv.z, bv.w};
#pragma unroll
            for (int i = 0; i < 4; ++i)
#pragma unroll
                for (int j = 0; j < 4; ++j) acc[i][j] += a[i] * b[j];
        }
        __syncthreads();
    }

#pragma unroll
    for (int i = 0; i < 4; ++i) {
        int row = bm + ty * 4 + i;
        if (row >= M) continue;
        float s = addend ? invdeg[row] : 0.f;
#pragma unroll
        for (int j = 0; j < 4; ++j) {
            int col = bn + tx * 4 + j;
            float v = acc[i][j];
            if (bias) v += bias[col];
            if (addend) v += addend[(size_t)row * N + col] * s;
            if (applySigmoid) v = 1.0f / (1.0f + expf(-v));
            C[(size_t)row * N + col] = v;
        }
    }
}

extern "C" void kernel_launch(void* const* d_in, const int* in_sizes, int n_in,
                              void* d_out, int out_size, void* d_ws, size_t ws_size,
                              hipStream_t stream) {
    const float* x        = (const float*)d_in[0];
    const int*   src      = (const int*)d_in[1];
    const int*   dst      = (const int*)d_in[2];
    const float* W_self1  = (const float*)d_in[3];
    const float* W_neigh1 = (const float*)d_in[4];
    const float* b1       = (const float*)d_in[5];
    const float* W_self2  = (const float*)d_in[6];
    const float* W_neigh2 = (const float*)d_in[7];
    const float* b2       = (const float*)d_in[8];
    float* out = (float*)d_out;

    // workspace layout
    char* ws = (char*)d_ws;
    float* invdeg = (float*)ws;                      ws += (size_t)N_NODES * 4;
    float* buf128 = (float*)ws;                      ws += (size_t)N_NODES * F_IN * 4;   // 51.2 MB
    float* h      = (float*)ws;                      ws += (size_t)N_NODES * F_HID * 4;  // 102.4 MB
    int* rowptr   = (int*)ws;                        ws += (size_t)(N_NODES + 1) * 4;
    int* cursor   = (int*)ws;                        ws += (size_t)N_NODES * 4;
    int* cnt      = (int*)ws;                        ws += (size_t)N_NODES * 4;
    int* blockSums= (int*)ws;                        ws += 256 * 4;
    int* csr_src  = (int*)ws;                        ws += (size_t)N_EDGES * 4;

    const int SCAN_NB = (N_NODES + 1023) / 1024;  // 98

    // ---- CSR build ----
    hipMemsetAsync(cnt, 0, (size_t)N_NODES * sizeof(int), stream);
    deg_count_kernel<<<(N_EDGES + 255) / 256, 256, 0, stream>>>(dst, cnt, N_EDGES);
    invdeg_kernel<<<(N_NODES + 255) / 256, 256, 0, stream>>>(cnt, invdeg, N_NODES);
    scan1_kernel<<<SCAN_NB, 1024, 0, stream>>>(cnt, rowptr, blockSums, N_NODES);
    scan2_kernel<<<1, 128, 0, stream>>>(blockSums, SCAN_NB);
    scan3_kernel<<<SCAN_NB, 1024, 0, stream>>>(rowptr, cursor, blockSums, N_NODES);
    fill_csr_kernel<<<(N_EDGES + 255) / 256, 256, 0, stream>>>(src, dst, cursor, csr_src, N_EDGES);

    // ---- layer 1: gather x (128-wide), then h = sigmoid([x | agg/deg] @ [Ws1;Wn1] + b1) ----
    gather_kernel<F_IN><<<(N_NODES + 3) / 4, 256, 0, stream>>>(x, rowptr, csr_src, buf128, N_NODES);
    {
        dim3 grid((N_NODES + BM - 1) / BM, F_HID / BN);
        gemm_cat_kernel<<<grid, 256, 0, stream>>>(
            x, F_IN, buf128, F_IN, invdeg, W_self1, W_neigh1, b1, nullptr, h,
            N_NODES, F_HID, F_IN, 2 * F_IN, 1);
    }

    // ---- layer 2 (transform-first): t = h @ W_neigh2 (into d_out as scratch) ----
    {
        dim3 grid((N_NODES + BM - 1) / BM, F_OUT / BN);
        gemm_cat_kernel<<<grid, 256, 0, stream>>>(
            h, F_HID, nullptr, 0, invdeg, W_neigh2, nullptr, nullptr, nullptr, out,
            N_NODES, F_OUT, F_HID, F_HID, 0);
    }
    // gather t (128-wide) into buf128
    gather_kernel<F_OUT><<<(N_NODES + 3) / 4, 256, 0, stream>>>(out, rowptr, csr_src, buf128, N_NODES);
    // out = h @ W_self2 + buf128*invdeg + b2
    {
        dim3 grid((N_NODES + BM - 1) / BM, F_OUT / BN);
        gemm_cat_kernel<<<grid, 256, 0, stream>>>(
            h, F_HID, nullptr, 0, invdeg, W_self2, nullptr, b2, buf128, out,
            N_NODES, F_OUT, F_HID, F_HID, 0);
    }
}

// Round 3
// 660.081 us; speedup vs baseline: 10.9051x; 1.4141x over previous
//
#include <hip/hip_runtime.h>
#include <hip/hip_bf16.h>

#define N_NODES 100000
#define N_EDGES 1600000
#define F_IN 128
#define F_HID 256
#define F_OUT 128

typedef unsigned short ushort_t;
typedef __attribute__((ext_vector_type(4))) float f32x4;
typedef __attribute__((ext_vector_type(8))) short bf16x8;

#define GAS __attribute__((address_space(1)))
#define LAS __attribute__((address_space(3)))

__device__ __forceinline__ float bf2f(ushort_t u) {
    unsigned int x = ((unsigned int)u) << 16;
    return __builtin_bit_cast(float, x);
}
__device__ __forceinline__ ushort_t f2bf(float f) {
    unsigned int x = __builtin_bit_cast(unsigned int, f);
    unsigned int r = (x + 0x7fffu + ((x >> 16) & 1u)) >> 16;
    return (ushort_t)r;
}

// ---------------- CSR build ----------------
__global__ __launch_bounds__(256) void deg_count_kernel(const int* __restrict__ dst,
                                                        int* __restrict__ cnt, int n) {
    int i = blockIdx.x * 256 + threadIdx.x;
    if (i < n) atomicAdd(&cnt[dst[i]], 1);
}

__global__ __launch_bounds__(256) void invdeg_kernel(const int* __restrict__ cnt,
                                                     float* __restrict__ inv, int n) {
    int i = blockIdx.x * 256 + threadIdx.x;
    if (i < n) inv[i] = 1.0f / fmaxf((float)cnt[i], 1.0f);
}

__global__ __launch_bounds__(1024) void scan1_kernel(const int* __restrict__ cnt,
                                                     int* __restrict__ rowptr,
                                                     int* __restrict__ blockSums, int n) {
    __shared__ int tmp[1024];
    int tid = threadIdx.x;
    int i = blockIdx.x * 1024 + tid;
    int v = (i < n) ? cnt[i] : 0;
    tmp[tid] = v;
    __syncthreads();
#pragma unroll
    for (int off = 1; off < 1024; off <<= 1) {
        int t = (tid >= off) ? tmp[tid - off] : 0;
        __syncthreads();
        tmp[tid] += t;
        __syncthreads();
    }
    if (i < n) rowptr[i] = tmp[tid] - v;
    if (tid == 1023) blockSums[blockIdx.x] = tmp[1023];
}

__global__ __launch_bounds__(128) void scan2_kernel(int* __restrict__ blockSums, int nb) {
    __shared__ int tmp[128];
    int tid = threadIdx.x;
    int v = (tid < nb) ? blockSums[tid] : 0;
    tmp[tid] = v;
    __syncthreads();
#pragma unroll
    for (int off = 1; off < 128; off <<= 1) {
        int t = (tid >= off) ? tmp[tid - off] : 0;
        __syncthreads();
        tmp[tid] += t;
        __syncthreads();
    }
    if (tid < nb) blockSums[tid] = tmp[tid] - v;
}

__global__ __launch_bounds__(1024) void scan3_kernel(int* __restrict__ rowptr,
                                                     int* __restrict__ cursor,
                                                     const int* __restrict__ blockSums, int n) {
    int i = blockIdx.x * 1024 + threadIdx.x;
    if (i < n) {
        int v = rowptr[i] + blockSums[blockIdx.x];
        rowptr[i] = v;
        cursor[i] = v;
    }
    if (i == 0) rowptr[n] = N_EDGES;
}

__global__ __launch_bounds__(256) void fill_csr_kernel(const int* __restrict__ src,
                                                       const int* __restrict__ dst,
                                                       int* __restrict__ cursor,
                                                       int* __restrict__ csr_src, int n) {
    int i = blockIdx.x * 256 + threadIdx.x;
    if (i < n) {
        int p = atomicAdd(&cursor[dst[i]], 1);
        csr_src[p] = src[i];
    }
}

// ---------------- fp32 -> bf16 converts ----------------
// x (N,128) fp32 -> A1[:, 0:128] bf16 (A1 row stride 256)
__global__ __launch_bounds__(256) void convert_x_kernel(const float* __restrict__ x,
                                                        ushort_t* __restrict__ A1, int n4) {
    int i = blockIdx.x * 256 + threadIdx.x;
    if (i >= n4) return;
    int e = i * 4;
    int row = e >> 7;
    int col = e & 127;
    float4 v = *(const float4*)(x + (size_t)row * F_IN + col);
    ushort4 o;
    o.x = f2bf(v.x); o.y = f2bf(v.y); o.z = f2bf(v.z); o.w = f2bf(v.w);
    *(ushort4*)(A1 + (size_t)row * 256 + col) = o;
}

// Wt[n][k] = bf16( k<Kx ? W1[k][n] : W2[k-Kx][n] )   (W row-major (K,N))
__global__ __launch_bounds__(256) void wtrans_kernel(const float* __restrict__ W1,
                                                     const float* __restrict__ W2,
                                                     ushort_t* __restrict__ Wt,
                                                     int Kx, int Ktot, int N) {
    int i = blockIdx.x * 256 + threadIdx.x;
    if (i >= N * Ktot) return;
    int n = i / Ktot, k = i - n * Ktot;
    float v = (k < Kx) ? W1[(size_t)k * N + n] : W2[(size_t)(k - Kx) * N + n];
    Wt[(size_t)n * Ktot + k] = f2bf(v);
}

// ---------------- gather (mean aggregate), bf16 in/out ----------------
// one wave per node, lane owns 2 bf16 columns
__global__ __launch_bounds__(256) void gather_bf16_kernel(
    const ushort_t* __restrict__ Hsrc, int ldh,
    const int* __restrict__ rowptr, const int* __restrict__ csr_src,
    const float* __restrict__ invdeg,
    ushort_t* __restrict__ outp, int ldo, int nNodes) {
    int lane = threadIdx.x & 63;
    int node = blockIdx.x * 4 + (threadIdx.x >> 6);
    if (node >= nNodes) return;
    int start = rowptr[node], end = rowptr[node + 1];
    float a0 = 0.f, a1 = 0.f;
    for (int e = start; e < end; ++e) {
        int s = csr_src[e];
        unsigned int v = *(const unsigned int*)(Hsrc + (size_t)s * ldh + lane * 2);
        a0 += bf2f((ushort_t)(v & 0xffffu));
        a1 += bf2f((ushort_t)(v >> 16));
    }
    float sc = invdeg[node];
    unsigned int p = (unsigned int)f2bf(a0 * sc) | ((unsigned int)f2bf(a1 * sc) << 16);
    *(unsigned int*)(outp + (size_t)node * ldo + lane * 2) = p;
}

// ---------------- bf16 MFMA GEMM ----------------
// C = A[M][K] @ Bt[N][K]^T ; 128x128 tile, 4 waves x (64x64), BK=64.
// mode 0: bf16 out, +bias, sigmoid   (layer-1 h)
// mode 1: bf16 out                   (t = h @ Wn2)
// mode 2: f32 out, +bias, +addend    (final)
__global__ __launch_bounds__(256) void gemm_mfma_kernel(
    const ushort_t* __restrict__ A,
    const ushort_t* __restrict__ Bt,
    const float* __restrict__ bias,
    const ushort_t* __restrict__ addend,
    void* __restrict__ Cout,
    int M, int N, int K, int mode) {
    __shared__ ushort_t As[128 * 64];
    __shared__ ushort_t Bs[128 * 64];
    int tid = threadIdx.x;
    int lane = tid & 63, wid = tid >> 6;
    int l15 = lane & 15, kgrp = lane >> 4, l7 = lane & 7, l8 = lane >> 3;
    int bm = blockIdx.x * 128, bn = blockIdx.y * 128;
    int wr = (wid >> 1) * 64, wc = (wid & 1) * 64;

    f32x4 acc[4][4] = {};

    for (int k0 = 0; k0 < K; k0 += 64) {
        // stage A,B tiles: chunk c = wid*4+t covers rows [c*8, c*8+8), 1KB each.
        // LDS dest linear (base + lane*16); global source column inverse-swizzled
        // so that swizzled ds_reads below see A[row][k] (rule 21).
#pragma unroll
        for (int t = 0; t < 4; ++t) {
            int c = wid * 4 + t;
            int row = c * 8 + l8;
            int scol = ((l7 ^ (row & 7)) << 3);  // element offset of this lane's 16B
            int ar = bm + row; if (ar > M - 1) ar = M - 1;
            __builtin_amdgcn_global_load_lds(
                (const GAS void*)(A + (size_t)ar * K + k0 + scol),
                (LAS void*)(&As[c * 512]), 16, 0, 0);
            int br = bn + row;  // N % 128 == 0
            __builtin_amdgcn_global_load_lds(
                (const GAS void*)(Bt + (size_t)br * K + k0 + scol),
                (LAS void*)(&Bs[c * 512]), 16, 0, 0);
        }
        __syncthreads();
#pragma unroll
        for (int kk = 0; kk < 2; ++kk) {
            bf16x8 af[4], bfv[4];
#pragma unroll
            for (int mi = 0; mi < 4; ++mi) {
                int row = wr + mi * 16 + l15;
                int kel = (kk * 32 + kgrp * 8) ^ ((row & 7) << 3);
                af[mi] = *(const bf16x8*)(&As[row * 64 + kel]);
            }
#pragma unroll
            for (int ni = 0; ni < 4; ++ni) {
                int row = wc + ni * 16 + l15;
                int kel = (kk * 32 + kgrp * 8) ^ ((row & 7) << 3);
                bfv[ni] = *(const bf16x8*)(&Bs[row * 64 + kel]);
            }
#pragma unroll
            for (int mi = 0; mi < 4; ++mi)
#pragma unroll
                for (int ni = 0; ni < 4; ++ni)
                    acc[mi][ni] = __builtin_amdgcn_mfma_f32_16x16x32_bf16(
                        af[mi], bfv[ni], acc[mi][ni], 0, 0, 0);
        }
        __syncthreads();
    }

    // epilogue: C/D layout col = lane&15, row = (lane>>4)*4 + reg
#pragma unroll
    for (int mi = 0; mi < 4; ++mi) {
#pragma unroll
        for (int ni = 0; ni < 4; ++ni) {
            int gcol = bn + wc + ni * 16 + l15;
#pragma unroll
            for (int r = 0; r < 4; ++r) {
                int grow = bm + wr + mi * 16 + kgrp * 4 + r;
                if (grow >= M) continue;
                float v = acc[mi][ni][r];
                if (mode == 0) {
                    v += bias[gcol];
                    v = 1.0f / (1.0f + __expf(-v));
                    ((ushort_t*)Cout)[(size_t)grow * N + gcol] = f2bf(v);
                } else if (mode == 1) {
                    ((ushort_t*)Cout)[(size_t)grow * N + gcol] = f2bf(v);
                } else {
                    v += bias[gcol] + bf2f(addend[(size_t)grow * N + gcol]);
                    ((float*)Cout)[(size_t)grow * N + gcol] = v;
                }
            }
        }
    }
}

extern "C" void kernel_launch(void* const* d_in, const int* in_sizes, int n_in,
                              void* d_out, int out_size, void* d_ws, size_t ws_size,
                              hipStream_t stream) {
    const float* x        = (const float*)d_in[0];
    const int*   src      = (const int*)d_in[1];
    const int*   dst      = (const int*)d_in[2];
    const float* W_self1  = (const float*)d_in[3];
    const float* W_neigh1 = (const float*)d_in[4];
    const float* b1       = (const float*)d_in[5];
    const float* W_self2  = (const float*)d_in[6];
    const float* W_neigh2 = (const float*)d_in[7];
    const float* b2       = (const float*)d_in[8];
    float* out = (float*)d_out;

    // ---- workspace layout (256B aligned sections) ----
    char* p = (char*)d_ws;
    auto alloc = [&](size_t bytes) { char* r = p; p += (bytes + 255) & ~(size_t)255; return r; };
    float*    invdeg   = (float*)alloc((size_t)N_NODES * 4);
    ushort_t* A1       = (ushort_t*)alloc((size_t)N_NODES * 256 * 2);  // [x | agg] bf16
    ushort_t* h        = (ushort_t*)alloc((size_t)N_NODES * 256 * 2);
    ushort_t* t        = (ushort_t*)alloc((size_t)N_NODES * 128 * 2);
    ushort_t* addend   = (ushort_t*)alloc((size_t)N_NODES * 128 * 2);
    ushort_t* Wt1      = (ushort_t*)alloc((size_t)256 * 256 * 2);
    ushort_t* Wtn2     = (ushort_t*)alloc((size_t)128 * 256 * 2);
    ushort_t* Wts2     = (ushort_t*)alloc((size_t)128 * 256 * 2);
    int* rowptr        = (int*)alloc((size_t)(N_NODES + 1) * 4);
    int* cursor        = (int*)alloc((size_t)N_NODES * 4);
    int* cnt           = (int*)alloc((size_t)N_NODES * 4);
    int* blockSums     = (int*)alloc(1024);
    int* csr_src       = (int*)alloc((size_t)N_EDGES * 4);

    const int SCAN_NB = (N_NODES + 1023) / 1024;

    // ---- converts (independent of CSR) ----
    convert_x_kernel<<<(N_NODES * F_IN / 4 + 255) / 256, 256, 0, stream>>>(
        x, A1, N_NODES * F_IN / 4);
    wtrans_kernel<<<(256 * 256 + 255) / 256, 256, 0, stream>>>(
        W_self1, W_neigh1, Wt1, 128, 256, 256);
    wtrans_kernel<<<(128 * 256 + 255) / 256, 256, 0, stream>>>(
        W_neigh2, nullptr, Wtn2, 256, 256, 128);
    wtrans_kernel<<<(128 * 256 + 255) / 256, 256, 0, stream>>>(
        W_self2, nullptr, Wts2, 256, 256, 128);

    // ---- CSR build ----
    hipMemsetAsync(cnt, 0, (size_t)N_NODES * sizeof(int), stream);
    deg_count_kernel<<<(N_EDGES + 255) / 256, 256, 0, stream>>>(dst, cnt, N_EDGES);
    invdeg_kernel<<<(N_NODES + 255) / 256, 256, 0, stream>>>(cnt, invdeg, N_NODES);
    scan1_kernel<<<SCAN_NB, 1024, 0, stream>>>(cnt, rowptr, blockSums, N_NODES);
    scan2_kernel<<<1, 128, 0, stream>>>(blockSums, SCAN_NB);
    scan3_kernel<<<SCAN_NB, 1024, 0, stream>>>(rowptr, cursor, blockSums, N_NODES);
    fill_csr_kernel<<<(N_EDGES + 255) / 256, 256, 0, stream>>>(src, dst, cursor, csr_src, N_EDGES);

    // ---- layer 1: gather xb into A1[:,128:256] (mean), then h = sigmoid(A1 @ Wt1 + b1) ----
    gather_bf16_kernel<<<(N_NODES + 3) / 4, 256, 0, stream>>>(
        A1, 256, rowptr, csr_src, invdeg, A1 + 128, 256, N_NODES);
    {
        dim3 grid((N_NODES + 127) / 128, 256 / 128);
        gemm_mfma_kernel<<<grid, 256, 0, stream>>>(A1, Wt1, b1, nullptr, h,
                                                   N_NODES, 256, 256, 0);
    }

    // ---- layer 2 (transform-first): t = h @ Wn2 ; addend = mean-gather(t) ----
    {
        dim3 grid((N_NODES + 127) / 128, 1);
        gemm_mfma_kernel<<<grid, 256, 0, stream>>>(h, Wtn2, nullptr, nullptr, t,
                                                   N_NODES, 128, 256, 1);
    }
    gather_bf16_kernel<<<(N_NODES + 3) / 4, 256, 0, stream>>>(
        t, 128, rowptr, csr_src, invdeg, addend, 128, N_NODES);
    // ---- out = h @ Ws2 + addend + b2 (fp32) ----
    {
        dim3 grid((N_NODES + 127) / 128, 1);
        gemm_mfma_kernel<<<grid, 256, 0, stream>>>(h, Wts2, b2, addend, out,
                                                   N_NODES, 128, 256, 2);
    }
}

// Round 4
// 464.880 us; speedup vs baseline: 15.4841x; 1.4199x over previous
//
#include <hip/hip_runtime.h>
#include <hip/hip_bf16.h>

#define N_NODES 100000
#define N_EDGES 1600000
#define F_IN 128
#define F_HID 256
#define F_OUT 128

typedef unsigned short ushort_t;
typedef __attribute__((ext_vector_type(4))) float f32x4;
typedef __attribute__((ext_vector_type(8))) short bf16x8;

#define GAS __attribute__((address_space(1)))
#define LAS __attribute__((address_space(3)))

__device__ __forceinline__ float bf2f(ushort_t u) {
    unsigned int x = ((unsigned int)u) << 16;
    return __builtin_bit_cast(float, x);
}
__device__ __forceinline__ ushort_t f2bf(float f) {
    unsigned int x = __builtin_bit_cast(unsigned int, f);
    unsigned int r = (x + 0x7fffu + ((x >> 16) & 1u)) >> 16;
    return (ushort_t)r;
}

// ---------------- CSR build ----------------
__global__ __launch_bounds__(256) void deg_count_kernel(const int* __restrict__ dst,
                                                        int* __restrict__ cnt, int n) {
    int i = blockIdx.x * 256 + threadIdx.x;
    if (i < n) atomicAdd(&cnt[dst[i]], 1);
}

__global__ __launch_bounds__(256) void invdeg_kernel(const int* __restrict__ cnt,
                                                     float* __restrict__ inv, int n) {
    int i = blockIdx.x * 256 + threadIdx.x;
    if (i < n) inv[i] = 1.0f / fmaxf((float)cnt[i], 1.0f);
}

__global__ __launch_bounds__(1024) void scan1_kernel(const int* __restrict__ cnt,
                                                     int* __restrict__ rowptr,
                                                     int* __restrict__ blockSums, int n) {
    __shared__ int tmp[1024];
    int tid = threadIdx.x;
    int i = blockIdx.x * 1024 + tid;
    int v = (i < n) ? cnt[i] : 0;
    tmp[tid] = v;
    __syncthreads();
#pragma unroll
    for (int off = 1; off < 1024; off <<= 1) {
        int t = (tid >= off) ? tmp[tid - off] : 0;
        __syncthreads();
        tmp[tid] += t;
        __syncthreads();
    }
    if (i < n) rowptr[i] = tmp[tid] - v;
    if (tid == 1023) blockSums[blockIdx.x] = tmp[1023];
}

__global__ __launch_bounds__(128) void scan2_kernel(int* __restrict__ blockSums, int nb) {
    __shared__ int tmp[128];
    int tid = threadIdx.x;
    int v = (tid < nb) ? blockSums[tid] : 0;
    tmp[tid] = v;
    __syncthreads();
#pragma unroll
    for (int off = 1; off < 128; off <<= 1) {
        int t = (tid >= off) ? tmp[tid - off] : 0;
        __syncthreads();
        tmp[tid] += t;
        __syncthreads();
    }
    if (tid < nb) blockSums[tid] = tmp[tid] - v;
}

__global__ __launch_bounds__(1024) void scan3_kernel(int* __restrict__ rowptr,
                                                     int* __restrict__ cursor,
                                                     const int* __restrict__ blockSums, int n) {
    int i = blockIdx.x * 1024 + threadIdx.x;
    if (i < n) {
        int v = rowptr[i] + blockSums[blockIdx.x];
        rowptr[i] = v;
        cursor[i] = v;
    }
    if (i == 0) rowptr[n] = N_EDGES;
}

__global__ __launch_bounds__(256) void fill_csr_kernel(const int* __restrict__ src,
                                                       const int* __restrict__ dst,
                                                       int* __restrict__ cursor,
                                                       int* __restrict__ csr_src, int n) {
    int i = blockIdx.x * 256 + threadIdx.x;
    if (i < n) {
        int p = atomicAdd(&cursor[dst[i]], 1);
        csr_src[p] = src[i];
    }
}

// ---------------- fp32 -> bf16 converts ----------------
__global__ __launch_bounds__(256) void convert_x_kernel(const float* __restrict__ x,
                                                        ushort_t* __restrict__ A1, int n4) {
    int i = blockIdx.x * 256 + threadIdx.x;
    if (i >= n4) return;
    int e = i * 4;
    int row = e >> 7;
    int col = e & 127;
    float4 v = *(const float4*)(x + (size_t)row * F_IN + col);
    ushort4 o;
    o.x = f2bf(v.x); o.y = f2bf(v.y); o.z = f2bf(v.z); o.w = f2bf(v.w);
    *(ushort4*)(A1 + (size_t)row * 256 + col) = o;
}

// Wt[n][k] = bf16( k<Kx ? W1[k][n] : W2[k-Kx][n] )  -- stack along K
__global__ __launch_bounds__(256) void wtransK_kernel(const float* __restrict__ W1,
                                                      const float* __restrict__ W2,
                                                      ushort_t* __restrict__ Wt,
                                                      int Kx, int Ktot, int N) {
    int i = blockIdx.x * 256 + threadIdx.x;
    if (i >= N * Ktot) return;
    int n = i / Ktot, k = i - n * Ktot;
    float v = (k < Kx) ? W1[(size_t)k * N + n] : W2[(size_t)(k - Kx) * N + n];
    Wt[(size_t)n * Ktot + k] = f2bf(v);
}

// Wt[n][k]: n<Nh -> Wa[k][n], else Wb[k][n-Nh]  -- stack along N (both (K,Nh) row-major)
__global__ __launch_bounds__(256) void wtransN_kernel(const float* __restrict__ Wa,
                                                      const float* __restrict__ Wb,
                                                      ushort_t* __restrict__ Wt,
                                                      int K, int Nh) {
    int i = blockIdx.x * 256 + threadIdx.x;
    if (i >= 2 * Nh * K) return;
    int n = i / K, k = i - n * K;
    const float* W = (n < Nh) ? Wa : Wb;
    int nn = (n < Nh) ? n : n - Nh;
    Wt[(size_t)n * K + k] = f2bf(W[(size_t)k * Nh + nn]);
}

// ---------------- 16-lane-per-edge gather ----------------
// one wave per node; lane group (lane>>4) owns one edge, each lane loads 16B.
// MODE 0: write bf16 mean (128 wide) ; MODE 1: out = uself + bias + invdeg*sum (fp32)
#define ACC8(v)                                                     \
    acc[0] += bf2f((ushort_t)((v).x & 0xffffu));                    \
    acc[1] += bf2f((ushort_t)((v).x >> 16));                        \
    acc[2] += bf2f((ushort_t)((v).y & 0xffffu));                    \
    acc[3] += bf2f((ushort_t)((v).y >> 16));                        \
    acc[4] += bf2f((ushort_t)((v).z & 0xffffu));                    \
    acc[5] += bf2f((ushort_t)((v).z >> 16));                        \
    acc[6] += bf2f((ushort_t)((v).w & 0xffffu));                    \
    acc[7] += bf2f((ushort_t)((v).w >> 16));

template <int MODE>
__global__ __launch_bounds__(256) void gather16_kernel(
    const ushort_t* __restrict__ H, int ldh,
    const int* __restrict__ rowptr, const int* __restrict__ csr_src,
    const float* __restrict__ invdeg,
    const ushort_t* __restrict__ uself, int ldu,
    const float* __restrict__ bias,
    void* __restrict__ outp, int ldo, int nNodes) {
    int lane = threadIdx.x & 63;
    int node = blockIdx.x * 4 + (threadIdx.x >> 6);
    if (node >= nNodes) return;
    int grp = lane >> 4, sub = lane & 15;
    int start = rowptr[node], end = rowptr[node + 1];
    const size_t cofs = (size_t)sub * 8;
    float acc[8] = {};
    for (int e = start + grp; e < end; e += 8) {
        int s1 = csr_src[e];
        uint4 v1 = *(const uint4*)(H + (size_t)s1 * ldh + cofs);
        int e2 = e + 4;
        bool p2 = (e2 < end);
        int s2 = p2 ? csr_src[e2] : s1;
        uint4 v2 = *(const uint4*)(H + (size_t)s2 * ldh + cofs);
        ACC8(v1);
        if (p2) { ACC8(v2); }
    }
#pragma unroll
    for (int j = 0; j < 8; ++j) {
        acc[j] += __shfl_xor(acc[j], 16);
        acc[j] += __shfl_xor(acc[j], 32);
    }
    if (grp == 0) {
        float sc = invdeg[node];
        if (MODE == 0) {
            uint4 o;
            o.x = (unsigned)f2bf(acc[0] * sc) | ((unsigned)f2bf(acc[1] * sc) << 16);
            o.y = (unsigned)f2bf(acc[2] * sc) | ((unsigned)f2bf(acc[3] * sc) << 16);
            o.z = (unsigned)f2bf(acc[4] * sc) | ((unsigned)f2bf(acc[5] * sc) << 16);
            o.w = (unsigned)f2bf(acc[6] * sc) | ((unsigned)f2bf(acc[7] * sc) << 16);
            *(uint4*)((ushort_t*)outp + (size_t)node * ldo + cofs) = o;
        } else {
            uint4 us = *(const uint4*)(uself + (size_t)node * ldu + cofs);
            float4 o0, o1;
            o0.x = acc[0] * sc + bf2f((ushort_t)(us.x & 0xffffu)) + bias[cofs + 0];
            o0.y = acc[1] * sc + bf2f((ushort_t)(us.x >> 16)) + bias[cofs + 1];
            o0.z = acc[2] * sc + bf2f((ushort_t)(us.y & 0xffffu)) + bias[cofs + 2];
            o0.w = acc[3] * sc + bf2f((ushort_t)(us.y >> 16)) + bias[cofs + 3];
            o1.x = acc[4] * sc + bf2f((ushort_t)(us.z & 0xffffu)) + bias[cofs + 4];
            o1.y = acc[5] * sc + bf2f((ushort_t)(us.z >> 16)) + bias[cofs + 5];
            o1.z = acc[6] * sc + bf2f((ushort_t)(us.w & 0xffffu)) + bias[cofs + 6];
            o1.w = acc[7] * sc + bf2f((ushort_t)(us.w >> 16)) + bias[cofs + 7];
            float* op = (float*)outp + (size_t)node * ldo + cofs;
            *(float4*)op = o0;
            *(float4*)(op + 4) = o1;
        }
    }
}

// ---------------- bf16 MFMA GEMM ----------------
// C = A[M][K] @ Bt[N][K]^T ; 128x128 tile, 4 waves x (64x64), BK=64.
// mode 0: bf16 out, +bias, sigmoid ; mode 1: bf16 out
__global__ __launch_bounds__(256) void gemm_mfma_kernel(
    const ushort_t* __restrict__ A,
    const ushort_t* __restrict__ Bt,
    const float* __restrict__ bias,
    ushort_t* __restrict__ Cout,
    int M, int N, int K, int mode) {
    __shared__ ushort_t As[128 * 64];
    __shared__ ushort_t Bs[128 * 64];
    int tid = threadIdx.x;
    int lane = tid & 63, wid = tid >> 6;
    int l15 = lane & 15, kgrp = lane >> 4, l7 = lane & 7, l8 = lane >> 3;
    int bm = blockIdx.x * 128, bn = blockIdx.y * 128;
    int wr = (wid >> 1) * 64, wc = (wid & 1) * 64;

    f32x4 acc[4][4] = {};

    for (int k0 = 0; k0 < K; k0 += 64) {
#pragma unroll
        for (int t = 0; t < 4; ++t) {
            int c = wid * 4 + t;
            int row = c * 8 + l8;
            int scol = ((l7 ^ (row & 7)) << 3);
            int ar = bm + row; if (ar > M - 1) ar = M - 1;
            __builtin_amdgcn_global_load_lds(
                (const GAS void*)(A + (size_t)ar * K + k0 + scol),
                (LAS void*)(&As[c * 512]), 16, 0, 0);
            int br = bn + row;
            __builtin_amdgcn_global_load_lds(
                (const GAS void*)(Bt + (size_t)br * K + k0 + scol),
                (LAS void*)(&Bs[c * 512]), 16, 0, 0);
        }
        __syncthreads();
#pragma unroll
        for (int kk = 0; kk < 2; ++kk) {
            bf16x8 af[4], bfv[4];
#pragma unroll
            for (int mi = 0; mi < 4; ++mi) {
                int row = wr + mi * 16 + l15;
                int kel = (kk * 32 + kgrp * 8) ^ ((row & 7) << 3);
                af[mi] = *(const bf16x8*)(&As[row * 64 + kel]);
            }
#pragma unroll
            for (int ni = 0; ni < 4; ++ni) {
                int row = wc + ni * 16 + l15;
                int kel = (kk * 32 + kgrp * 8) ^ ((row & 7) << 3);
                bfv[ni] = *(const bf16x8*)(&Bs[row * 64 + kel]);
            }
#pragma unroll
            for (int mi = 0; mi < 4; ++mi)
#pragma unroll
                for (int ni = 0; ni < 4; ++ni)
                    acc[mi][ni] = __builtin_amdgcn_mfma_f32_16x16x32_bf16(
                        af[mi], bfv[ni], acc[mi][ni], 0, 0, 0);
        }
        __syncthreads();
    }

#pragma unroll
    for (int mi = 0; mi < 4; ++mi) {
#pragma unroll
        for (int ni = 0; ni < 4; ++ni) {
            int gcol = bn + wc + ni * 16 + l15;
#pragma unroll
            for (int r = 0; r < 4; ++r) {
                int grow = bm + wr + mi * 16 + kgrp * 4 + r;
                if (grow >= M) continue;
                float v = acc[mi][ni][r];
                if (mode == 0) {
                    v += bias[gcol];
                    v = 1.0f / (1.0f + __expf(-v));
                }
                Cout[(size_t)grow * N + gcol] = f2bf(v);
            }
        }
    }
}

extern "C" void kernel_launch(void* const* d_in, const int* in_sizes, int n_in,
                              void* d_out, int out_size, void* d_ws, size_t ws_size,
                              hipStream_t stream) {
    const float* x        = (const float*)d_in[0];
    const int*   src      = (const int*)d_in[1];
    const int*   dst      = (const int*)d_in[2];
    const float* W_self1  = (const float*)d_in[3];
    const float* W_neigh1 = (const float*)d_in[4];
    const float* b1       = (const float*)d_in[5];
    const float* W_self2  = (const float*)d_in[6];
    const float* W_neigh2 = (const float*)d_in[7];
    const float* b2       = (const float*)d_in[8];
    float* out = (float*)d_out;

    // ---- workspace layout ----
    char* p = (char*)d_ws;
    auto alloc = [&](size_t bytes) { char* r = p; p += (bytes + 255) & ~(size_t)255; return r; };
    float*    invdeg   = (float*)alloc((size_t)N_NODES * 4);
    ushort_t* A1       = (ushort_t*)alloc((size_t)N_NODES * 256 * 2);  // [x | agg]
    ushort_t* h        = (ushort_t*)alloc((size_t)N_NODES * 256 * 2);
    ushort_t* u        = (ushort_t*)alloc((size_t)N_NODES * 256 * 2);  // [u_self | u_neigh]
    ushort_t* Wt1      = (ushort_t*)alloc((size_t)256 * 256 * 2);
    ushort_t* Wt2      = (ushort_t*)alloc((size_t)256 * 256 * 2);
    int* rowptr        = (int*)alloc((size_t)(N_NODES + 1) * 4);
    int* cursor        = (int*)alloc((size_t)N_NODES * 4);
    int* cnt           = (int*)alloc((size_t)N_NODES * 4);
    int* blockSums     = (int*)alloc(1024);
    int* csr_src       = (int*)alloc((size_t)N_EDGES * 4);

    const int SCAN_NB = (N_NODES + 1023) / 1024;

    // ---- converts ----
    convert_x_kernel<<<(N_NODES * F_IN / 4 + 255) / 256, 256, 0, stream>>>(
        x, A1, N_NODES * F_IN / 4);
    wtransK_kernel<<<(256 * 256 + 255) / 256, 256, 0, stream>>>(
        W_self1, W_neigh1, Wt1, 128, 256, 256);
    wtransN_kernel<<<(256 * 256 + 255) / 256, 256, 0, stream>>>(
        W_self2, W_neigh2, Wt2, 256, 128);

    // ---- CSR build ----
    hipMemsetAsync(cnt, 0, (size_t)N_NODES * sizeof(int), stream);
    deg_count_kernel<<<(N_EDGES + 255) / 256, 256, 0, stream>>>(dst, cnt, N_EDGES);
    invdeg_kernel<<<(N_NODES + 255) / 256, 256, 0, stream>>>(cnt, invdeg, N_NODES);
    scan1_kernel<<<SCAN_NB, 1024, 0, stream>>>(cnt, rowptr, blockSums, N_NODES);
    scan2_kernel<<<1, 128, 0, stream>>>(blockSums, SCAN_NB);
    scan3_kernel<<<SCAN_NB, 1024, 0, stream>>>(rowptr, cursor, blockSums, N_NODES);
    fill_csr_kernel<<<(N_EDGES + 255) / 256, 256, 0, stream>>>(src, dst, cursor, csr_src, N_EDGES);

    // ---- layer 1: gather x -> A1[:,128:256], then h = sigmoid(A1 @ Wt1 + b1) ----
    gather16_kernel<0><<<(N_NODES + 3) / 4, 256, 0, stream>>>(
        A1, 256, rowptr, csr_src, invdeg, nullptr, 0, nullptr, A1 + 128, 256, N_NODES);
    {
        dim3 grid((N_NODES + 127) / 128, 2);
        gemm_mfma_kernel<<<grid, 256, 0, stream>>>(A1, Wt1, b1, h, N_NODES, 256, 256, 0);
    }

    // ---- layer 2: u = h @ [Ws2|Wn2] (one pass) ----
    {
        dim3 grid((N_NODES + 127) / 128, 2);
        gemm_mfma_kernel<<<grid, 256, 0, stream>>>(h, Wt2, nullptr, u, N_NODES, 256, 256, 1);
    }
    // ---- out = u_self + b2 + invdeg * gather(u_neigh) ----
    gather16_kernel<1><<<(N_NODES + 3) / 4, 256, 0, stream>>>(
        u + 128, 256, rowptr, csr_src, invdeg, u, 256, b2, out, 128, N_NODES);
}

// Round 6
// 424.683 us; speedup vs baseline: 16.9497x; 1.0947x over previous
//
#include <hip/hip_runtime.h>
#include <hip/hip_bf16.h>

#define N_NODES 100000
#define N_EDGES 1600000
#define F_IN 128
#define F_HID 256
#define F_OUT 128

typedef unsigned short ushort_t;
typedef __attribute__((ext_vector_type(4))) float f32x4;
typedef __attribute__((ext_vector_type(8))) short bf16x8;

#define GAS __attribute__((address_space(1)))
#define LAS __attribute__((address_space(3)))

__device__ __forceinline__ float bf2f(ushort_t u) {
    unsigned int x = ((unsigned int)u) << 16;
    return __builtin_bit_cast(float, x);
}
__device__ __forceinline__ ushort_t f2bf(float f) {
    unsigned int x = __builtin_bit_cast(unsigned int, f);
    unsigned int r = (x + 0x7fffu + ((x >> 16) & 1u)) >> 16;
    return (ushort_t)r;
}

// ---------------- CSR build ----------------
__global__ __launch_bounds__(256) void deg_count_kernel(const int* __restrict__ dst,
                                                        int* __restrict__ cnt, int n) {
    int i = blockIdx.x * 256 + threadIdx.x;
    if (i < n) atomicAdd(&cnt[dst[i]], 1);
}

__global__ __launch_bounds__(256) void invdeg_kernel(const int* __restrict__ cnt,
                                                     float* __restrict__ inv, int n) {
    int i = blockIdx.x * 256 + threadIdx.x;
    if (i < n) inv[i] = 1.0f / fmaxf((float)cnt[i], 1.0f);
}

__global__ __launch_bounds__(1024) void scan1_kernel(const int* __restrict__ cnt,
                                                     int* __restrict__ rowptr,
                                                     int* __restrict__ blockSums, int n) {
    __shared__ int tmp[1024];
    int tid = threadIdx.x;
    int i = blockIdx.x * 1024 + tid;
    int v = (i < n) ? cnt[i] : 0;
    tmp[tid] = v;
    __syncthreads();
#pragma unroll
    for (int off = 1; off < 1024; off <<= 1) {
        int t = (tid >= off) ? tmp[tid - off] : 0;
        __syncthreads();
        tmp[tid] += t;
        __syncthreads();
    }
    if (i < n) rowptr[i] = tmp[tid] - v;
    if (tid == 1023) blockSums[blockIdx.x] = tmp[1023];
}

__global__ __launch_bounds__(128) void scan2_kernel(int* __restrict__ blockSums, int nb) {
    __shared__ int tmp[128];
    int tid = threadIdx.x;
    int v = (tid < nb) ? blockSums[tid] : 0;
    tmp[tid] = v;
    __syncthreads();
#pragma unroll
    for (int off = 1; off < 128; off <<= 1) {
        int t = (tid >= off) ? tmp[tid - off] : 0;
        __syncthreads();
        tmp[tid] += t;
        __syncthreads();
    }
    if (tid < nb) blockSums[tid] = tmp[tid] - v;
}

__global__ __launch_bounds__(1024) void scan3_kernel(int* __restrict__ rowptr,
                                                     int* __restrict__ cursor,
                                                     const int* __restrict__ blockSums, int n) {
    int i = blockIdx.x * 1024 + threadIdx.x;
    if (i < n) {
        int v = rowptr[i] + blockSums[blockIdx.x];
        rowptr[i] = v;
        cursor[i] = v;
    }
    if (i == 0) rowptr[n] = N_EDGES;
}

// banded fill: band-major block order so concurrently-resident blocks write a
// ~1.6MB csr_src region that lives in L2 (write-scatter 105MB -> ~15MB HBM).
#define FILL_BANDS 4
#define FILL_BPP ((N_EDGES + 255) / 256)  // blocks per band pass
__global__ __launch_bounds__(256) void fill_csr_banded_kernel(
    const int* __restrict__ src, const int* __restrict__ dst,
    int* __restrict__ cursor, int* __restrict__ csr_src, int n) {
    int band = blockIdx.x / FILL_BPP;
    int i = (blockIdx.x - band * FILL_BPP) * 256 + threadIdx.x;
    if (i >= n) return;
    int d = dst[i];
    const int bandSz = N_NODES / FILL_BANDS;  // 25000
    int lo = band * bandSz;
    int hi = (band == FILL_BANDS - 1) ? N_NODES : lo + bandSz;
    if (d >= lo && d < hi) {
        int p = atomicAdd(&cursor[d], 1);
        csr_src[p] = src[i];
    }
}

// ---------------- fp32 -> bf16 converts ----------------
__global__ __launch_bounds__(256) void convert_x_kernel(const float* __restrict__ x,
                                                        ushort_t* __restrict__ A1, int n4) {
    int i = blockIdx.x * 256 + threadIdx.x;
    if (i >= n4) return;
    int e = i * 4;
    int row = e >> 7;
    int col = e & 127;
    f32x4 v = __builtin_nontemporal_load((const f32x4*)(x + (size_t)row * F_IN + col));
    ushort4 o;
    o.x = f2bf(v.x); o.y = f2bf(v.y); o.z = f2bf(v.z); o.w = f2bf(v.w);
    *(ushort4*)(A1 + (size_t)row * 256 + col) = o;
}

// Wt[n][k] = bf16( k<Kx ? W1[k][n] : W2[k-Kx][n] )  -- stack along K
__global__ __launch_bounds__(256) void wtransK_kernel(const float* __restrict__ W1,
                                                      const float* __restrict__ W2,
                                                      ushort_t* __restrict__ Wt,
                                                      int Kx, int Ktot, int N) {
    int i = blockIdx.x * 256 + threadIdx.x;
    if (i >= N * Ktot) return;
    int n = i / Ktot, k = i - n * Ktot;
    float v = (k < Kx) ? W1[(size_t)k * N + n] : W2[(size_t)(k - Kx) * N + n];
    Wt[(size_t)n * Ktot + k] = f2bf(v);
}

// Wt[n][k]: n<Nh -> Wa[k][n], else Wb[k][n-Nh]  -- stack along N
__global__ __launch_bounds__(256) void wtransN_kernel(const float* __restrict__ Wa,
                                                      const float* __restrict__ Wb,
                                                      ushort_t* __restrict__ Wt,
                                                      int K, int Nh) {
    int i = blockIdx.x * 256 + threadIdx.x;
    if (i >= 2 * Nh * K) return;
    int n = i / K, k = i - n * K;
    const float* W = (n < Nh) ? Wa : Wb;
    int nn = (n < Nh) ? n : n - Nh;
    Wt[(size_t)n * K + k] = f2bf(W[(size_t)k * Nh + nn]);
}

// ---------------- 16-lane-per-edge gather, 4 edges per group-iter ----------------
#define ACC8(v)                                                     \
    acc[0] += bf2f((ushort_t)((v).x & 0xffffu));                    \
    acc[1] += bf2f((ushort_t)((v).x >> 16));                        \
    acc[2] += bf2f((ushort_t)((v).y & 0xffffu));                    \
    acc[3] += bf2f((ushort_t)((v).y >> 16));                        \
    acc[4] += bf2f((ushort_t)((v).z & 0xffffu));                    \
    acc[5] += bf2f((ushort_t)((v).z >> 16));                        \
    acc[6] += bf2f((ushort_t)((v).w & 0xffffu));                    \
    acc[7] += bf2f((ushort_t)((v).w >> 16));

template <int MODE>
__global__ __launch_bounds__(256) void gather16_kernel(
    const ushort_t* __restrict__ H, int ldh,
    const int* __restrict__ rowptr, const int* __restrict__ csr_src,
    const float* __restrict__ invdeg,
    const ushort_t* __restrict__ uself, int ldu,
    const float* __restrict__ bias,
    void* __restrict__ outp, int ldo, int nNodes) {
    int lane = threadIdx.x & 63;
    int node = blockIdx.x * 4 + (threadIdx.x >> 6);
    if (node >= nNodes) return;
    int grp = lane >> 4, sub = lane & 15;
    int start = rowptr[node], end = rowptr[node + 1];
    const size_t cofs = (size_t)sub * 8;
    float acc[8] = {};
    // 16 edges in flight per wave: 4 groups x 4 predicated loads
    for (int e = start + grp; e < end; e += 16) {
        int s0 = csr_src[e];
        uint4 v0 = *(const uint4*)(H + (size_t)s0 * ldh + cofs);
        bool p1 = (e + 4) < end;
        int s1 = p1 ? csr_src[e + 4] : s0;
        uint4 v1 = *(const uint4*)(H + (size_t)s1 * ldh + cofs);
        bool p2 = (e + 8) < end;
        int s2 = p2 ? csr_src[e + 8] : s0;
        uint4 v2 = *(const uint4*)(H + (size_t)s2 * ldh + cofs);
        bool p3 = (e + 12) < end;
        int s3 = p3 ? csr_src[e + 12] : s0;
        uint4 v3 = *(const uint4*)(H + (size_t)s3 * ldh + cofs);
        ACC8(v0);
        if (p1) { ACC8(v1); }
        if (p2) { ACC8(v2); }
        if (p3) { ACC8(v3); }
    }
#pragma unroll
    for (int j = 0; j < 8; ++j) {
        acc[j] += __shfl_xor(acc[j], 16);
        acc[j] += __shfl_xor(acc[j], 32);
    }
    if (grp == 0) {
        float sc = invdeg[node];
        if (MODE == 0) {
            uint4 o;
            o.x = (unsigned)f2bf(acc[0] * sc) | ((unsigned)f2bf(acc[1] * sc) << 16);
            o.y = (unsigned)f2bf(acc[2] * sc) | ((unsigned)f2bf(acc[3] * sc) << 16);
            o.z = (unsigned)f2bf(acc[4] * sc) | ((unsigned)f2bf(acc[5] * sc) << 16);
            o.w = (unsigned)f2bf(acc[6] * sc) | ((unsigned)f2bf(acc[7] * sc) << 16);
            *(uint4*)((ushort_t*)outp + (size_t)node * ldo + cofs) = o;
        } else {
            uint4 us = *(const uint4*)(uself + (size_t)node * ldu + cofs);
            f32x4 o0, o1;
            o0.x = acc[0] * sc + bf2f((ushort_t)(us.x & 0xffffu)) + bias[cofs + 0];
            o0.y = acc[1] * sc + bf2f((ushort_t)(us.x >> 16)) + bias[cofs + 1];
            o0.z = acc[2] * sc + bf2f((ushort_t)(us.y & 0xffffu)) + bias[cofs + 2];
            o0.w = acc[3] * sc + bf2f((ushort_t)(us.y >> 16)) + bias[cofs + 3];
            o1.x = acc[4] * sc + bf2f((ushort_t)(us.z & 0xffffu)) + bias[cofs + 4];
            o1.y = acc[5] * sc + bf2f((ushort_t)(us.z >> 16)) + bias[cofs + 5];
            o1.z = acc[6] * sc + bf2f((ushort_t)(us.w & 0xffffu)) + bias[cofs + 6];
            o1.w = acc[7] * sc + bf2f((ushort_t)(us.w >> 16)) + bias[cofs + 7];
            float* op = (float*)outp + (size_t)node * ldo + cofs;
            __builtin_nontemporal_store(o0, (f32x4*)op);
            __builtin_nontemporal_store(o1, (f32x4*)(op + 4));
        }
    }
}

// ---------------- bf16 MFMA GEMM ----------------
// C = A[M][K] @ Bt[N][K]^T ; 128x128 tile, 4 waves x (64x64), BK=64.
// mode 0: bf16 out, +bias, sigmoid ; mode 1: bf16 out
__global__ __launch_bounds__(256) void gemm_mfma_kernel(
    const ushort_t* __restrict__ A,
    const ushort_t* __restrict__ Bt,
    const float* __restrict__ bias,
    ushort_t* __restrict__ Cout,
    int M, int N, int K, int mode) {
    __shared__ ushort_t As[128 * 64];
    __shared__ ushort_t Bs[128 * 64];
    int tid = threadIdx.x;
    int lane = tid & 63, wid = tid >> 6;
    int l15 = lane & 15, kgrp = lane >> 4, l7 = lane & 7, l8 = lane >> 3;
    int bm = blockIdx.x * 128, bn = blockIdx.y * 128;
    int wr = (wid >> 1) * 64, wc = (wid & 1) * 64;

    f32x4 acc[4][4] = {};

    for (int k0 = 0; k0 < K; k0 += 64) {
#pragma unroll
        for (int t = 0; t < 4; ++t) {
            int c = wid * 4 + t;
            int row = c * 8 + l8;
            int scol = ((l7 ^ (row & 7)) << 3);
            int ar = bm + row; if (ar > M - 1) ar = M - 1;
            __builtin_amdgcn_global_load_lds(
                (const GAS void*)(A + (size_t)ar * K + k0 + scol),
                (LAS void*)(&As[c * 512]), 16, 0, 0);
            int br = bn + row;
            __builtin_amdgcn_global_load_lds(
                (const GAS void*)(Bt + (size_t)br * K + k0 + scol),
                (LAS void*)(&Bs[c * 512]), 16, 0, 0);
        }
        __syncthreads();
#pragma unroll
        for (int kk = 0; kk < 2; ++kk) {
            bf16x8 af[4], bfv[4];
#pragma unroll
            for (int mi = 0; mi < 4; ++mi) {
                int row = wr + mi * 16 + l15;
                int kel = (kk * 32 + kgrp * 8) ^ ((row & 7) << 3);
                af[mi] = *(const bf16x8*)(&As[row * 64 + kel]);
            }
#pragma unroll
            for (int ni = 0; ni < 4; ++ni) {
                int row = wc + ni * 16 + l15;
                int kel = (kk * 32 + kgrp * 8) ^ ((row & 7) << 3);
                bfv[ni] = *(const bf16x8*)(&Bs[row * 64 + kel]);
            }
#pragma unroll
            for (int mi = 0; mi < 4; ++mi)
#pragma unroll
                for (int ni = 0; ni < 4; ++ni)
                    acc[mi][ni] = __builtin_amdgcn_mfma_f32_16x16x32_bf16(
                        af[mi], bfv[ni], acc[mi][ni], 0, 0, 0);
        }
        __syncthreads();
    }

#pragma unroll
    for (int mi = 0; mi < 4; ++mi) {
#pragma unroll
        for (int ni = 0; ni < 4; ++ni) {
            int gcol = bn + wc + ni * 16 + l15;
#pragma unroll
            for (int r = 0; r < 4; ++r) {
                int grow = bm + wr + mi * 16 + kgrp * 4 + r;
                if (grow >= M) continue;
                float v = acc[mi][ni][r];
                if (mode == 0) {
                    v += bias[gcol];
                    v = 1.0f / (1.0f + __expf(-v));
                }
                Cout[(size_t)grow * N + gcol] = f2bf(v);
            }
        }
    }
}

extern "C" void kernel_launch(void* const* d_in, const int* in_sizes, int n_in,
                              void* d_out, int out_size, void* d_ws, size_t ws_size,
                              hipStream_t stream) {
    const float* x        = (const float*)d_in[0];
    const int*   src      = (const int*)d_in[1];
    const int*   dst      = (const int*)d_in[2];
    const float* W_self1  = (const float*)d_in[3];
    const float* W_neigh1 = (const float*)d_in[4];
    const float* b1       = (const float*)d_in[5];
    const float* W_self2  = (const float*)d_in[6];
    const float* W_neigh2 = (const float*)d_in[7];
    const float* b2       = (const float*)d_in[8];
    float* out = (float*)d_out;

    // ---- workspace layout ----
    char* p = (char*)d_ws;
    auto alloc = [&](size_t bytes) { char* r = p; p += (bytes + 255) & ~(size_t)255; return r; };
    float*    invdeg   = (float*)alloc((size_t)N_NODES * 4);
    ushort_t* A1       = (ushort_t*)alloc((size_t)N_NODES * 256 * 2);  // [x | agg]
    ushort_t* h        = (ushort_t*)alloc((size_t)N_NODES * 256 * 2);
    ushort_t* u        = (ushort_t*)alloc((size_t)N_NODES * 256 * 2);  // [u_self | u_neigh]
    ushort_t* Wt1      = (ushort_t*)alloc((size_t)256 * 256 * 2);
    ushort_t* Wt2      = (ushort_t*)alloc((size_t)256 * 256 * 2);
    int* rowptr        = (int*)alloc((size_t)(N_NODES + 1) * 4);
    int* cursor        = (int*)alloc((size_t)N_NODES * 4);
    int* cnt           = (int*)alloc((size_t)N_NODES * 4);
    int* blockSums     = (int*)alloc(1024);
    int* csr_src       = (int*)alloc((size_t)N_EDGES * 4);

    const int SCAN_NB = (N_NODES + 1023) / 1024;

    // ---- converts ----
    convert_x_kernel<<<(N_NODES * F_IN / 4 + 255) / 256, 256, 0, stream>>>(
        x, A1, N_NODES * F_IN / 4);
    wtransK_kernel<<<(256 * 256 + 255) / 256, 256, 0, stream>>>(
        W_self1, W_neigh1, Wt1, 128, 256, 256);
    wtransN_kernel<<<(256 * 256 + 255) / 256, 256, 0, stream>>>(
        W_self2, W_neigh2, Wt2, 256, 128);

    // ---- CSR build ----
    hipMemsetAsync(cnt, 0, (size_t)N_NODES * sizeof(int), stream);
    deg_count_kernel<<<(N_EDGES + 255) / 256, 256, 0, stream>>>(dst, cnt, N_EDGES);
    invdeg_kernel<<<(N_NODES + 255) / 256, 256, 0, stream>>>(cnt, invdeg, N_NODES);
    scan1_kernel<<<SCAN_NB, 1024, 0, stream>>>(cnt, rowptr, blockSums, N_NODES);
    scan2_kernel<<<1, 128, 0, stream>>>(blockSums, SCAN_NB);
    scan3_kernel<<<SCAN_NB, 1024, 0, stream>>>(rowptr, cursor, blockSums, N_NODES);
    fill_csr_banded_kernel<<<FILL_BPP * FILL_BANDS, 256, 0, stream>>>(
        src, dst, cursor, csr_src, N_EDGES);

    // ---- layer 1: gather x -> A1[:,128:256], then h = sigmoid(A1 @ Wt1 + b1) ----
    gather16_kernel<0><<<(N_NODES + 3) / 4, 256, 0, stream>>>(
        A1, 256, rowptr, csr_src, invdeg, nullptr, 0, nullptr, A1 + 128, 256, N_NODES);
    {
        dim3 grid((N_NODES + 127) / 128, 2);
        gemm_mfma_kernel<<<grid, 256, 0, stream>>>(A1, Wt1, b1, h, N_NODES, 256, 256, 0);
    }

    // ---- layer 2: u = h @ [Ws2|Wn2] (one pass) ----
    {
        dim3 grid((N_NODES + 127) / 128, 2);
        gemm_mfma_kernel<<<grid, 256, 0, stream>>>(h, Wt2, nullptr, u, N_NODES, 256, 256, 1);
    }
    // ---- out = u_self + b2 + invdeg * gather(u_neigh) ----
    gather16_kernel<1><<<(N_NODES + 3) / 4, 256, 0, stream>>>(
        u + 128, 256, rowptr, csr_src, invdeg, u, 256, b2, out, 128, N_NODES);
}

// Round 7
// 395.135 us; speedup vs baseline: 18.2171x; 1.0748x over previous
//
#include <hip/hip_runtime.h>
#include <hip/hip_bf16.h>

#define N_NODES 100000
#define N_EDGES 1600000
#define F_IN 128
#define F_HID 256
#define F_OUT 128

typedef unsigned short ushort_t;
typedef __attribute__((ext_vector_type(4))) float f32x4;
typedef __attribute__((ext_vector_type(8))) short bf16x8;

#define GAS __attribute__((address_space(1)))
#define LAS __attribute__((address_space(3)))

__device__ __forceinline__ float bf2f(ushort_t u) {
    unsigned int x = ((unsigned int)u) << 16;
    return __builtin_bit_cast(float, x);
}
__device__ __forceinline__ ushort_t f2bf(float f) {
    unsigned int x = __builtin_bit_cast(unsigned int, f);
    unsigned int r = (x + 0x7fffu + ((x >> 16) & 1u)) >> 16;
    return (ushort_t)r;
}

// ---------------- CSR build ----------------
__global__ __launch_bounds__(256) void deg_count_kernel(const int* __restrict__ dst,
                                                        int* __restrict__ cnt, int n) {
    int i = blockIdx.x * 256 + threadIdx.x;
    if (i < n) atomicAdd(&cnt[dst[i]], 1);
}

__global__ __launch_bounds__(256) void invdeg_kernel(const int* __restrict__ cnt,
                                                     float* __restrict__ inv, int n) {
    int i = blockIdx.x * 256 + threadIdx.x;
    if (i < n) inv[i] = 1.0f / fmaxf((float)cnt[i], 1.0f);
}

__global__ __launch_bounds__(1024) void scan1_kernel(const int* __restrict__ cnt,
                                                     int* __restrict__ rowptr,
                                                     int* __restrict__ blockSums, int n) {
    __shared__ int tmp[1024];
    int tid = threadIdx.x;
    int i = blockIdx.x * 1024 + tid;
    int v = (i < n) ? cnt[i] : 0;
    tmp[tid] = v;
    __syncthreads();
#pragma unroll
    for (int off = 1; off < 1024; off <<= 1) {
        int t = (tid >= off) ? tmp[tid - off] : 0;
        __syncthreads();
        tmp[tid] += t;
        __syncthreads();
    }
    if (i < n) rowptr[i] = tmp[tid] - v;
    if (tid == 1023) blockSums[blockIdx.x] = tmp[1023];
}

__global__ __launch_bounds__(128) void scan2_kernel(int* __restrict__ blockSums, int nb) {
    __shared__ int tmp[128];
    int tid = threadIdx.x;
    int v = (tid < nb) ? blockSums[tid] : 0;
    tmp[tid] = v;
    __syncthreads();
#pragma unroll
    for (int off = 1; off < 128; off <<= 1) {
        int t = (tid >= off) ? tmp[tid - off] : 0;
        __syncthreads();
        tmp[tid] += t;
        __syncthreads();
    }
    if (tid < nb) blockSums[tid] = tmp[tid] - v;
}

__global__ __launch_bounds__(1024) void scan3_kernel(int* __restrict__ rowptr,
                                                     int* __restrict__ cursor,
                                                     const int* __restrict__ blockSums, int n) {
    int i = blockIdx.x * 1024 + threadIdx.x;
    if (i < n) {
        int v = rowptr[i] + blockSums[blockIdx.x];
        rowptr[i] = v;
        cursor[i] = v;
    }
    if (i == 0) rowptr[n] = N_EDGES;
}

// XCD-pinned fill: band = blockIdx.x & 7 rides the round-robin block->XCD
// mapping, so each csr_src band region (~800KB) is written by ONE XCD's L2
// and lines fill completely before eviction (round-6: cross-XCD partial
// lines caused 91MB HBM write for 6.4MB of data).
#define XBANDS 8
#define BAND_SZ (N_NODES / XBANDS)  // 12500
__global__ __launch_bounds__(256) void fill_csr_xcd_kernel(
    const int* __restrict__ src, const int* __restrict__ dst,
    int* __restrict__ cursor, int* __restrict__ csr_src, int n) {
    int band = blockIdx.x & 7;
    int i = (blockIdx.x >> 3) * 256 + threadIdx.x;
    if (i >= n) return;
    int d = dst[i];
    if (d >= band * BAND_SZ && d < (band + 1) * BAND_SZ) {
        int p = atomicAdd(&cursor[d], 1);
        csr_src[p] = src[i];
    }
}

// ---------------- fp32 -> bf16 converts ----------------
__global__ __launch_bounds__(256) void convert_x_kernel(const float* __restrict__ x,
                                                        ushort_t* __restrict__ A1, int n4) {
    int i = blockIdx.x * 256 + threadIdx.x;
    if (i >= n4) return;
    int e = i * 4;
    int row = e >> 7;
    int col = e & 127;
    f32x4 v = __builtin_nontemporal_load((const f32x4*)(x + (size_t)row * F_IN + col));
    ushort4 o;
    o.x = f2bf(v.x); o.y = f2bf(v.y); o.z = f2bf(v.z); o.w = f2bf(v.w);
    *(ushort4*)(A1 + (size_t)row * 256 + col) = o;
}

// Wt[n][k] = bf16( k<Kx ? W1[k][n] : W2[k-Kx][n] )  -- stack along K
__global__ __launch_bounds__(256) void wtransK_kernel(const float* __restrict__ W1,
                                                      const float* __restrict__ W2,
                                                      ushort_t* __restrict__ Wt,
                                                      int Kx, int Ktot, int N) {
    int i = blockIdx.x * 256 + threadIdx.x;
    if (i >= N * Ktot) return;
    int n = i / Ktot, k = i - n * Ktot;
    float v = (k < Kx) ? W1[(size_t)k * N + n] : W2[(size_t)(k - Kx) * N + n];
    Wt[(size_t)n * Ktot + k] = f2bf(v);
}

// Wt[n][k]: n<Nh -> Wa[k][n], else Wb[k][n-Nh]  -- stack along N
__global__ __launch_bounds__(256) void wtransN_kernel(const float* __restrict__ Wa,
                                                      const float* __restrict__ Wb,
                                                      ushort_t* __restrict__ Wt,
                                                      int K, int Nh) {
    int i = blockIdx.x * 256 + threadIdx.x;
    if (i >= 2 * Nh * K) return;
    int n = i / K, k = i - n * K;
    const float* W = (n < Nh) ? Wa : Wb;
    int nn = (n < Nh) ? n : n - Nh;
    Wt[(size_t)n * K + k] = f2bf(W[(size_t)k * Nh + nn]);
}

// ---------------- 16-lane-per-edge gather, 4 edges per group-iter ----------------
#define ACC8(v)                                                     \
    acc[0] += bf2f((ushort_t)((v).x & 0xffffu));                    \
    acc[1] += bf2f((ushort_t)((v).x >> 16));                        \
    acc[2] += bf2f((ushort_t)((v).y & 0xffffu));                    \
    acc[3] += bf2f((ushort_t)((v).y >> 16));                        \
    acc[4] += bf2f((ushort_t)((v).z & 0xffffu));                    \
    acc[5] += bf2f((ushort_t)((v).z >> 16));                        \
    acc[6] += bf2f((ushort_t)((v).w & 0xffffu));                    \
    acc[7] += bf2f((ushort_t)((v).w >> 16));

template <int MODE>
__global__ __launch_bounds__(256) void gather16_kernel(
    const ushort_t* __restrict__ H, int ldh,
    const int* __restrict__ rowptr, const int* __restrict__ csr_src,
    const float* __restrict__ invdeg,
    const ushort_t* __restrict__ uself, int ldu,
    const float* __restrict__ bias,
    void* __restrict__ outp, int ldo, int nNodes) {
    int lane = threadIdx.x & 63;
    int node = blockIdx.x * 4 + (threadIdx.x >> 6);
    if (node >= nNodes) return;
    int grp = lane >> 4, sub = lane & 15;
    int start = rowptr[node], end = rowptr[node + 1];
    const size_t cofs = (size_t)sub * 8;
    float acc[8] = {};
    // 16 edges in flight per wave: 4 groups x 4 predicated loads
    for (int e = start + grp; e < end; e += 16) {
        int s0 = csr_src[e];
        uint4 v0 = *(const uint4*)(H + (size_t)s0 * ldh + cofs);
        bool p1 = (e + 4) < end;
        int s1 = p1 ? csr_src[e + 4] : s0;
        uint4 v1 = *(const uint4*)(H + (size_t)s1 * ldh + cofs);
        bool p2 = (e + 8) < end;
        int s2 = p2 ? csr_src[e + 8] : s0;
        uint4 v2 = *(const uint4*)(H + (size_t)s2 * ldh + cofs);
        bool p3 = (e + 12) < end;
        int s3 = p3 ? csr_src[e + 12] : s0;
        uint4 v3 = *(const uint4*)(H + (size_t)s3 * ldh + cofs);
        ACC8(v0);
        if (p1) { ACC8(v1); }
        if (p2) { ACC8(v2); }
        if (p3) { ACC8(v3); }
    }
#pragma unroll
    for (int j = 0; j < 8; ++j) {
        acc[j] += __shfl_xor(acc[j], 16);
        acc[j] += __shfl_xor(acc[j], 32);
    }
    if (grp == 0) {
        float sc = invdeg[node];
        if (MODE == 0) {
            uint4 o;
            o.x = (unsigned)f2bf(acc[0] * sc) | ((unsigned)f2bf(acc[1] * sc) << 16);
            o.y = (unsigned)f2bf(acc[2] * sc) | ((unsigned)f2bf(acc[3] * sc) << 16);
            o.z = (unsigned)f2bf(acc[4] * sc) | ((unsigned)f2bf(acc[5] * sc) << 16);
            o.w = (unsigned)f2bf(acc[6] * sc) | ((unsigned)f2bf(acc[7] * sc) << 16);
            *(uint4*)((ushort_t*)outp + (size_t)node * ldo + cofs) = o;
        } else {
            uint4 us = *(const uint4*)(uself + (size_t)node * ldu + cofs);
            f32x4 o0, o1;
            o0.x = acc[0] * sc + bf2f((ushort_t)(us.x & 0xffffu)) + bias[cofs + 0];
            o0.y = acc[1] * sc + bf2f((ushort_t)(us.x >> 16)) + bias[cofs + 1];
            o0.z = acc[2] * sc + bf2f((ushort_t)(us.y & 0xffffu)) + bias[cofs + 2];
            o0.w = acc[3] * sc + bf2f((ushort_t)(us.y >> 16)) + bias[cofs + 3];
            o1.x = acc[4] * sc + bf2f((ushort_t)(us.z & 0xffffu)) + bias[cofs + 4];
            o1.y = acc[5] * sc + bf2f((ushort_t)(us.z >> 16)) + bias[cofs + 5];
            o1.z = acc[6] * sc + bf2f((ushort_t)(us.w & 0xffffu)) + bias[cofs + 6];
            o1.w = acc[7] * sc + bf2f((ushort_t)(us.w >> 16)) + bias[cofs + 7];
            float* op = (float*)outp + (size_t)node * ldo + cofs;
            __builtin_nontemporal_store(o0, (f32x4*)op);
            __builtin_nontemporal_store(o1, (f32x4*)(op + 4));
        }
    }
}

// ---------------- bf16 MFMA GEMM ----------------
// C = A[M][K] @ Bt[N][K]^T ; 128x128 tile, 4 waves x (64x64), BK=64.
// mode 0: bf16 out, +bias, sigmoid ; mode 1: bf16 out
// Epilogue: per-wave LDS transpose (XOR-swizzled, conflict-free) -> b128 stores.
__global__ __launch_bounds__(256) void gemm_mfma_kernel(
    const ushort_t* __restrict__ A,
    const ushort_t* __restrict__ Bt,
    const float* __restrict__ bias,
    ushort_t* __restrict__ Cout,
    int M, int N, int K, int mode) {
    __shared__ ushort_t shmem[2 * 128 * 64];  // staging As|Bs; reused by epilogue
    ushort_t* As = shmem;
    ushort_t* Bs = shmem + 128 * 64;
    int tid = threadIdx.x;
    int lane = tid & 63, wid = tid >> 6;
    int l15 = lane & 15, kgrp = lane >> 4, l7 = lane & 7, l8 = lane >> 3;
    int bm = blockIdx.x * 128, bn = blockIdx.y * 128;
    int wr = (wid >> 1) * 64, wc = (wid & 1) * 64;

    f32x4 acc[4][4] = {};

    for (int k0 = 0; k0 < K; k0 += 64) {
#pragma unroll
        for (int t = 0; t < 4; ++t) {
            int c = wid * 4 + t;
            int row = c * 8 + l8;
            int scol = ((l7 ^ (row & 7)) << 3);
            int ar = bm + row; if (ar > M - 1) ar = M - 1;
            __builtin_amdgcn_global_load_lds(
                (const GAS void*)(A + (size_t)ar * K + k0 + scol),
                (LAS void*)(&As[c * 512]), 16, 0, 0);
            int br = bn + row;
            __builtin_amdgcn_global_load_lds(
                (const GAS void*)(Bt + (size_t)br * K + k0 + scol),
                (LAS void*)(&Bs[c * 512]), 16, 0, 0);
        }
        __syncthreads();
#pragma unroll
        for (int kk = 0; kk < 2; ++kk) {
            bf16x8 af[4], bfv[4];
#pragma unroll
            for (int mi = 0; mi < 4; ++mi) {
                int row = wr + mi * 16 + l15;
                int kel = (kk * 32 + kgrp * 8) ^ ((row & 7) << 3);
                af[mi] = *(const bf16x8*)(&As[row * 64 + kel]);
            }
#pragma unroll
            for (int ni = 0; ni < 4; ++ni) {
                int row = wc + ni * 16 + l15;
                int kel = (kk * 32 + kgrp * 8) ^ ((row & 7) << 3);
                bfv[ni] = *(const bf16x8*)(&Bs[row * 64 + kel]);
            }
#pragma unroll
            for (int mi = 0; mi < 4; ++mi)
#pragma unroll
                for (int ni = 0; ni < 4; ++ni)
                    acc[mi][ni] = __builtin_amdgcn_mfma_f32_16x16x32_bf16(
                        af[mi], bfv[ni], acc[mi][ni], 0, 0, 0);
        }
        __syncthreads();
    }

    // ---- epilogue: wave-local 64x64 transpose in LDS, then 16B stores ----
    // write: row lr = mi*16+kgrp*4+r, col lc = ni*16+l15, 8-col block XOR'd by
    // kgrp ((lr>>2)&3 == kgrp) -> kgrp groups hit disjoint bank ranges.
    ushort_t* my = shmem + wid * 4096;
#pragma unroll
    for (int mi = 0; mi < 4; ++mi) {
#pragma unroll
        for (int ni = 0; ni < 4; ++ni) {
            int gcol = bn + wc + ni * 16 + l15;
#pragma unroll
            for (int r = 0; r < 4; ++r) {
                float v = acc[mi][ni][r];
                if (mode == 0) {
                    v += bias[gcol];
                    v = 1.0f / (1.0f + __expf(-v));
                }
                int lr = mi * 16 + kgrp * 4 + r;
                int lc = (ni * 16 + l15) ^ (kgrp << 3);
                my[lr * 64 + lc] = f2bf(v);
            }
        }
    }
    // read back: lane handles col-block (lane&7), rows (lane>>3)+8*it
#pragma unroll
    for (int it = 0; it < 8; ++it) {
        int r2 = (lane >> 3) + it * 8;
        int c2 = ((lane & 7) << 3) ^ (((r2 >> 2) & 3) << 3);
        bf16x8 vv = *(const bf16x8*)(&my[r2 * 64 + c2]);
        int grow = bm + wr + r2;
        if (grow < M) {
            int gc = bn + wc + (c2 ^ (((r2 >> 2) & 3) << 3));
            *(bf16x8*)(&Cout[(size_t)grow * N + gc]) = vv;
        }
    }
}

extern "C" void kernel_launch(void* const* d_in, const int* in_sizes, int n_in,
                              void* d_out, int out_size, void* d_ws, size_t ws_size,
                              hipStream_t stream) {
    const float* x        = (const float*)d_in[0];
    const int*   src      = (const int*)d_in[1];
    const int*   dst      = (const int*)d_in[2];
    const float* W_self1  = (const float*)d_in[3];
    const float* W_neigh1 = (const float*)d_in[4];
    const float* b1       = (const float*)d_in[5];
    const float* W_self2  = (const float*)d_in[6];
    const float* W_neigh2 = (const float*)d_in[7];
    const float* b2       = (const float*)d_in[8];
    float* out = (float*)d_out;

    // ---- workspace layout ----
    char* p = (char*)d_ws;
    auto alloc = [&](size_t bytes) { char* r = p; p += (bytes + 255) & ~(size_t)255; return r; };
    float*    invdeg   = (float*)alloc((size_t)N_NODES * 4);
    ushort_t* A1       = (ushort_t*)alloc((size_t)N_NODES * 256 * 2);  // [x | agg]
    ushort_t* h        = (ushort_t*)alloc((size_t)N_NODES * 256 * 2);
    ushort_t* u        = (ushort_t*)alloc((size_t)N_NODES * 256 * 2);  // [u_self | u_neigh]
    ushort_t* Wt1      = (ushort_t*)alloc((size_t)256 * 256 * 2);
    ushort_t* Wt2      = (ushort_t*)alloc((size_t)256 * 256 * 2);
    int* rowptr        = (int*)alloc((size_t)(N_NODES + 1) * 4);
    int* cursor        = (int*)alloc((size_t)N_NODES * 4);
    int* cnt           = (int*)alloc((size_t)N_NODES * 4);
    int* blockSums     = (int*)alloc(1024);
    int* csr_src       = (int*)alloc((size_t)N_EDGES * 4);

    const int SCAN_NB = (N_NODES + 1023) / 1024;

    // ---- converts ----
    convert_x_kernel<<<(N_NODES * F_IN / 4 + 255) / 256, 256, 0, stream>>>(
        x, A1, N_NODES * F_IN / 4);
    wtransK_kernel<<<(256 * 256 + 255) / 256, 256, 0, stream>>>(
        W_self1, W_neigh1, Wt1, 128, 256, 256);
    wtransN_kernel<<<(256 * 256 + 255) / 256, 256, 0, stream>>>(
        W_self2, W_neigh2, Wt2, 256, 128);

    // ---- CSR build ----
    hipMemsetAsync(cnt, 0, (size_t)N_NODES * sizeof(int), stream);
    deg_count_kernel<<<(N_EDGES + 255) / 256, 256, 0, stream>>>(dst, cnt, N_EDGES);
    invdeg_kernel<<<(N_NODES + 255) / 256, 256, 0, stream>>>(cnt, invdeg, N_NODES);
    scan1_kernel<<<SCAN_NB, 1024, 0, stream>>>(cnt, rowptr, blockSums, N_NODES);
    scan2_kernel<<<1, 128, 0, stream>>>(blockSums, SCAN_NB);
    scan3_kernel<<<SCAN_NB, 1024, 0, stream>>>(rowptr, cursor, blockSums, N_NODES);
    fill_csr_xcd_kernel<<<((N_EDGES + 255) / 256) * XBANDS, 256, 0, stream>>>(
        src, dst, cursor, csr_src, N_EDGES);

    // ---- layer 1: gather x -> A1[:,128:256], then h = sigmoid(A1 @ Wt1 + b1) ----
    gather16_kernel<0><<<(N_NODES + 3) / 4, 256, 0, stream>>>(
        A1, 256, rowptr, csr_src, invdeg, nullptr, 0, nullptr, A1 + 128, 256, N_NODES);
    {
        dim3 grid((N_NODES + 127) / 128, 2);
        gemm_mfma_kernel<<<grid, 256, 0, stream>>>(A1, Wt1, b1, h, N_NODES, 256, 256, 0);
    }

    // ---- layer 2: u = h @ [Ws2|Wn2] (one pass) ----
    {
        dim3 grid((N_NODES + 127) / 128, 2);
        gemm_mfma_kernel<<<grid, 256, 0, stream>>>(h, Wt2, nullptr, u, N_NODES, 256, 256, 1);
    }
    // ---- out = u_self + b2 + invdeg * gather(u_neigh) ----
    gather16_kernel<1><<<(N_NODES + 3) / 4, 256, 0, stream>>>(
        u + 128, 256, rowptr, csr_src, invdeg, u, 256, b2, out, 128, N_NODES);
}